// Round 4
// baseline (2283.786 us; speedup 1.0000x reference)
//
#include <hip/hip_runtime.h>
#include <hip/hip_bf16.h>
#include <math.h>

typedef __hip_bfloat16 bf16;
typedef __attribute__((ext_vector_type(8))) short short8;
typedef __attribute__((ext_vector_type(4))) short short4v;
typedef __attribute__((ext_vector_type(4))) float f32x4;

#define NSEQ 2304
#define CDIM 256
#define NHD  4
#define DH   64

static __device__ __forceinline__ f32x4 mfma_bf16(short8 a, short8 b, f32x4 c) {
  return __builtin_amdgcn_mfma_f32_16x16x32_bf16(a, b, c, 0, 0, 0);
}
static __device__ __forceinline__ short8 ld8(const bf16* p) {
  return *reinterpret_cast<const short8*>(p);
}
static __device__ __forceinline__ float b2f(short v) {
  unsigned int u = ((unsigned int)(unsigned short)v) << 16;
  return __uint_as_float(u);
}

// ---------------- dtype probe: are float inputs fp32 or bf16? ----------------
// Read x as bf16; check EVEN-indexed elements. If the underlying data is fp32,
// even bf16 slots are low-mantissa bits (uniform random -> ~48% "insane").
// If data is bf16, all are ~N(0,1) -> sane. flag=1 means "inputs are fp32".
__global__ __launch_bounds__(256) void detect_kernel(const void* __restrict__ xraw,
                                                     int* __restrict__ flag) {
  int t = threadIdx.x;
  const unsigned short* s = (const unsigned short*)xraw;
  int bad = 0;
#pragma unroll
  for (int i = 0; i < 8; ++i) {
    unsigned idx = (((unsigned)(t * 8 + i)) * 9173u) & ((1u << 20) - 1);  // < 2^20
    unsigned short v = s[idx * 2];   // even element, short index < 2^21 (in-bounds either way)
    unsigned e = (v >> 7) & 0xFFu;   // bf16 exponent field
    if (e > 133u) bad++;             // |v| >= 64 or NaN/Inf -> implausible for x~N(0,1)
  }
  __shared__ int tot;
  if (t == 0) tot = 0;
  __syncthreads();
  atomicAdd(&tot, bad);
  __syncthreads();
  if (t == 0) flag[0] = (tot >= 16) ? 1 : 0;
}

// ---------------- convert any float input to a bf16 copy ----------------
__global__ __launch_bounds__(256) void cvt_kernel(const void* __restrict__ src,
                                                  bf16* __restrict__ dst, int n,
                                                  const int* __restrict__ flag) {
  int is32 = flag[0];
  int i = blockIdx.x * 256 + threadIdx.x;
  if (i >= n) return;
  if (is32) dst[i] = __float2bfloat16(((const float*)src)[i]);
  else      dst[i] = ((const bf16*)src)[i];
}

// ---------------- QKV GEMM: qkv = x @ Wqkv^T, scatter into Q,K,V ----------------
__global__ __launch_bounds__(256) void qkv_kernel(const bf16* __restrict__ X,
                                                  const bf16* __restrict__ Wqkv,
                                                  bf16* __restrict__ Q, bf16* __restrict__ K,
                                                  bf16* __restrict__ V) {
  int wave = threadIdx.x >> 6, lane = threadIdx.x & 63;
  int l15 = lane & 15, quad = lane >> 4;
  int m0 = (blockIdx.x * 4 + wave) * 16;
  int n0 = blockIdx.y * 16;
  const bf16* arow = X + (size_t)(m0 + l15) * CDIM + quad * 8;
  const bf16* brow = Wqkv + (size_t)(n0 + l15) * CDIM + quad * 8;
  f32x4 acc = {0.f, 0.f, 0.f, 0.f};
#pragma unroll
  for (int kk = 0; kk < CDIM; kk += 32)
    acc = mfma_bf16(ld8(arow + kk), ld8(brow + kk), acc);

  int col = n0 + l15;
  int which = col >> 8, rem = col & 255;
  int h = rem >> 6, d = rem & 63;
#pragma unroll
  for (int r = 0; r < 4; ++r) {
    int gm = m0 + quad * 4 + r;
    int b = gm / NSEQ, n = gm % NSEQ;
    int bh = b * NHD + h;
    bf16 val = __float2bfloat16(acc[r]);
    if (which == 0)      Q[((size_t)bh * NSEQ + n) * DH + d] = val;
    else if (which == 1) K[((size_t)bh * NSEQ + n) * DH + d] = val;
    else                 V[((size_t)bh * NSEQ + n) * DH + d] = val;
  }
}

// ---------------- RoPE (2D), in place on Q and K (precise math) ----------------
__global__ __launch_bounds__(256) void rope_kernel(bf16* __restrict__ Q, bf16* __restrict__ K,
                                                   const int* __restrict__ Wp) {
  int Wv = Wp[0];
  if (Wv <= 0 || Wv > 65536) Wv = 48;
  int t = blockIdx.x * 256 + threadIdx.x;   // 73728 rows * 32 pair-slots
  int p = t & 31;
  int row = t >> 5;
  int which = (row >= 16 * NSEQ) ? 1 : 0;
  int r2 = which ? row - 16 * NSEQ : row;
  int bh = r2 / NSEQ, n = r2 % NSEQ;
  int py = n / Wv, px = n - py * Wv;
  int part = p >> 4, i = p & 15;
  float pos = (float)(part ? px : py);
  int j0 = 2 * i;
  const float c = -9.210340371976184f / 32.0f;  // -ln(10000)/32
  float f0 = expf(c * (float)j0);
  float f1 = expf(c * (float)(j0 + 1));
  float s0, c0, s1, c1;
  sincosf(pos * f0, &s0, &c0);
  sincosf(pos * f1, &s1, &c1);
  bf16* base = (which ? K : Q) + ((size_t)bh * NSEQ + n) * DH + part * 32 + j0;
  float a  = __bfloat162float(base[0]);
  float bb = __bfloat162float(base[1]);
  base[0] = __float2bfloat16(a * c0 - bb * s0);
  base[1] = __float2bfloat16(bb * c1 + a * s1);
}

// ---------------- Boring attention: one block = 4 q-rows of one head ----------------
__global__ __launch_bounds__(256) void attn_simple(const bf16* __restrict__ Q, const bf16* __restrict__ K,
                                                   const bf16* __restrict__ V, bf16* __restrict__ AO) {
  __shared__ float sc[4][NSEQ];
  __shared__ float qs[4][DH];
  __shared__ float red[256];
  __shared__ float lrow[4];
  int bh = blockIdx.x;
  int r0 = blockIdx.y * 4;
  int t = threadIdx.x;
  const bf16* Qb = Q + (size_t)bh * NSEQ * DH;
  const bf16* Kb = K + (size_t)bh * NSEQ * DH;
  const bf16* Vb = V + (size_t)bh * NSEQ * DH;

  {
    int rr = t >> 6, d = t & 63;
    qs[rr][d] = __bfloat162float(Qb[(size_t)(r0 + rr) * DH + d]);
  }
  __syncthreads();

  for (int n = t; n < NSEQ; n += 256) {
    float s[4] = {0.f, 0.f, 0.f, 0.f};
#pragma unroll
    for (int j = 0; j < 8; ++j) {
      short8 kk = ld8(Kb + (size_t)n * DH + j * 8);
#pragma unroll
      for (int u = 0; u < 8; ++u) {
        float kf = b2f(kk[u]);
#pragma unroll
        for (int rr = 0; rr < 4; ++rr) s[rr] += qs[rr][j * 8 + u] * kf;
      }
    }
#pragma unroll
    for (int rr = 0; rr < 4; ++rr) sc[rr][n] = s[rr] * 0.125f;
  }
  __syncthreads();

  for (int rr = 0; rr < 4; ++rr) {
    float m = -1e30f;
    for (int n = t; n < NSEQ; n += 256) m = fmaxf(m, sc[rr][n]);
    red[t] = m;
    __syncthreads();
    for (int s2 = 128; s2 > 0; s2 >>= 1) {
      if (t < s2) red[t] = fmaxf(red[t], red[t + s2]);
      __syncthreads();
    }
    float mm = red[0];
    __syncthreads();
    float l = 0.f;
    for (int n = t; n < NSEQ; n += 256) {
      float pexp = expf(sc[rr][n] - mm);
      sc[rr][n] = pexp;
      l += pexp;
    }
    red[t] = l;
    __syncthreads();
    for (int s2 = 128; s2 > 0; s2 >>= 1) {
      if (t < s2) red[t] += red[t + s2];
      __syncthreads();
    }
    if (t == 0) lrow[rr] = red[0];
    __syncthreads();
  }

  {
    int rr = t >> 6, d = t & 63;
    float o = 0.f;
    for (int n = 0; n < NSEQ; ++n)
      o += sc[rr][n] * __bfloat162float(Vb[(size_t)n * DH + d]);
    o /= lrow[rr];
    int b = bh >> 2, h = bh & 3;
    AO[((size_t)b * NSEQ + (r0 + rr)) * CDIM + h * DH + d] = __float2bfloat16(o);
  }
}

// ---------------- Generic MFMA GEMM  out = A @ Wm^T (+epilogue), bf16 out ----------------
template <int KD, int EPI>
__global__ __launch_bounds__(256) void gemm16(const bf16* __restrict__ A, const bf16* __restrict__ Wm,
                                              const bf16* __restrict__ bias, const bf16* __restrict__ res,
                                              bf16* __restrict__ outp, int NC) {
  int wave = threadIdx.x >> 6, lane = threadIdx.x & 63;
  int l15 = lane & 15, quad = lane >> 4;
  int m0 = (blockIdx.x * 4 + wave) * 16;
  int n0 = blockIdx.y * 16;
  const bf16* arow = A + (size_t)(m0 + l15) * KD + quad * 8;
  const bf16* brow = Wm + (size_t)(n0 + l15) * KD + quad * 8;
  f32x4 acc = {0.f, 0.f, 0.f, 0.f};
#pragma unroll 8
  for (int kk = 0; kk < KD; kk += 32)
    acc = mfma_bf16(ld8(arow + kk), ld8(brow + kk), acc);

  int col = n0 + l15;
#pragma unroll
  for (int r = 0; r < 4; ++r) {
    int gm = m0 + quad * 4 + r;
    size_t idx = (size_t)gm * NC + col;
    if (EPI == 0) {
      outp[idx] = __float2bfloat16(acc[r] + __bfloat162float(res[idx]));
    } else if (EPI == 1) {
      float hv = acc[r] + __bfloat162float(bias[col]);
      float gv = 0.5f * hv * (1.f + erff(hv * 0.70710678118f));
      outp[idx] = __float2bfloat16(gv);
    } else {
      outp[idx] = __float2bfloat16(acc[r] + __bfloat162float(bias[col]) + __bfloat162float(res[idx]));
    }
  }
}

// ---------------- LayerNorm bf16->bf16 (one wave per row) ----------------
__global__ __launch_bounds__(256) void ln_kernel(const bf16* __restrict__ X, const bf16* __restrict__ g,
                                                 const bf16* __restrict__ bv, bf16* __restrict__ out) {
  int row = blockIdx.x * 4 + (threadIdx.x >> 6);
  int lane = threadIdx.x & 63;
  short4v raw = *reinterpret_cast<const short4v*>(X + (size_t)row * CDIM + lane * 4);
  float vv[4];
  float s = 0.f, sq = 0.f;
#pragma unroll
  for (int i = 0; i < 4; ++i) {
    float f = b2f(raw[i]);
    vv[i] = f; s += f; sq += f * f;
  }
#pragma unroll
  for (int off = 1; off < 64; off <<= 1) { s += __shfl_xor(s, off); sq += __shfl_xor(sq, off); }
  float mu = s * (1.f / CDIM);
  float var = sq * (1.f / CDIM) - mu * mu;
  float rstd = rsqrtf(var + 1e-5f);
#pragma unroll
  for (int i = 0; i < 4; ++i) {
    int c = lane * 4 + i;
    out[(size_t)row * CDIM + c] =
        __float2bfloat16((vv[i] - mu) * rstd * __bfloat162float(g[c]) + __bfloat162float(bv[c]));
  }
}

// ---------------- Final LayerNorm: bf16 in, flag-dependent dtype out ----------------
__global__ __launch_bounds__(256) void ln_out_kernel(const bf16* __restrict__ X, const bf16* __restrict__ g,
                                                     const bf16* __restrict__ bv, void* __restrict__ out,
                                                     const int* __restrict__ flag) {
  int is32 = flag[0];
  int row = blockIdx.x * 4 + (threadIdx.x >> 6);
  int lane = threadIdx.x & 63;
  short4v raw = *reinterpret_cast<const short4v*>(X + (size_t)row * CDIM + lane * 4);
  float vv[4];
  float s = 0.f, sq = 0.f;
#pragma unroll
  for (int i = 0; i < 4; ++i) {
    float f = b2f(raw[i]);
    vv[i] = f; s += f; sq += f * f;
  }
#pragma unroll
  for (int off = 1; off < 64; off <<= 1) { s += __shfl_xor(s, off); sq += __shfl_xor(sq, off); }
  float mu = s * (1.f / CDIM);
  float var = sq * (1.f / CDIM) - mu * mu;
  float rstd = rsqrtf(var + 1e-5f);
#pragma unroll
  for (int i = 0; i < 4; ++i) {
    int c = lane * 4 + i;
    size_t idx = (size_t)row * CDIM + c;
    float v = (vv[i] - mu) * rstd * __bfloat162float(g[c]) + __bfloat162float(bv[c]);
    if (is32) ((float*)out)[idx] = v;
    else      ((bf16*)out)[idx] = __float2bfloat16(v);
  }
}

extern "C" void kernel_launch(void* const* d_in, const int* in_sizes, int n_in,
                              void* d_out, int out_size, void* d_ws, size_t ws_size,
                              hipStream_t stream) {
  const int* Wp = (const int*)d_in[12];

  char* ws = (char*)d_ws;
  const size_t SZ = 4718592;  // 2304*4*256 bf16 bytes
  bf16* Qc  = (bf16*)(ws + 0 * SZ);
  bf16* Kc  = (bf16*)(ws + 1 * SZ);
  bf16* Vc  = (bf16*)(ws + 2 * SZ);
  bf16* AO  = (bf16*)(ws + 3 * SZ);
  bf16* F   = (bf16*)(ws + 4 * SZ);
  bf16* Y   = (bf16*)(ws + 5 * SZ);
  bf16* xc  = (bf16*)(ws + 6 * SZ);
  bf16* G   = (bf16*)(ws + 0);              // overlays Qc..AO (4*SZ exactly)
  bf16* Wqkvc  = (bf16*)(ws + 7 * SZ);                    // 393216 B
  bf16* Wprojc = (bf16*)(ws + 7 * SZ + 393216);           // 131072 B
  bf16* W1c    = (bf16*)(ws + 7 * SZ + 524288);           // 524288 B
  bf16* W2c    = (bf16*)(ws + 7 * SZ + 1048576);          // 524288 B
  bf16* bf1c   = (bf16*)(ws + 7 * SZ + 1572864);          // 2048 B
  bf16* g1c    = (bf16*)(ws + 7 * SZ + 1574912);
  bf16* b1c    = (bf16*)(ws + 7 * SZ + 1575424);
  bf16* g2c    = (bf16*)(ws + 7 * SZ + 1575936);
  bf16* b2c    = (bf16*)(ws + 7 * SZ + 1576448);
  bf16* bf2c   = (bf16*)(ws + 7 * SZ + 1576960);
  int*  flagp  = (int*)(ws + 7 * SZ + 1577472);
  bf16* outsc  = (bf16*)d_out;  // bf16 scratch region (fits in either dtype's buffer)

  detect_kernel<<<1, 256, 0, stream>>>(d_in[0], flagp);
  cvt_kernel<<<9216, 256, 0, stream>>>(d_in[0], xc, 2359296, flagp);
  cvt_kernel<<<768, 256, 0, stream>>>(d_in[1], Wqkvc, 196608, flagp);
  cvt_kernel<<<256, 256, 0, stream>>>(d_in[2], Wprojc, 65536, flagp);
  cvt_kernel<<<1, 256, 0, stream>>>(d_in[3], g1c, 256, flagp);
  cvt_kernel<<<1, 256, 0, stream>>>(d_in[4], b1c, 256, flagp);
  cvt_kernel<<<1, 256, 0, stream>>>(d_in[5], g2c, 256, flagp);
  cvt_kernel<<<1, 256, 0, stream>>>(d_in[6], b2c, 256, flagp);
  cvt_kernel<<<1024, 256, 0, stream>>>(d_in[7], W1c, 262144, flagp);
  cvt_kernel<<<4, 256, 0, stream>>>(d_in[8], bf1c, 1024, flagp);
  cvt_kernel<<<1024, 256, 0, stream>>>(d_in[9], W2c, 262144, flagp);
  cvt_kernel<<<1, 256, 0, stream>>>(d_in[10], bf2c, 256, flagp);

  qkv_kernel<<<dim3(144, 48), 256, 0, stream>>>(xc, Wqkvc, Qc, Kc, Vc);
  rope_kernel<<<9216, 256, 0, stream>>>(Qc, Kc, Wp);
  attn_simple<<<dim3(16, 576), 256, 0, stream>>>(Qc, Kc, Vc, AO);
  gemm16<256, 0><<<dim3(144, 16), 256, 0, stream>>>(AO, Wprojc, nullptr, xc, outsc, 256);
  ln_kernel<<<2304, 256, 0, stream>>>(outsc, g1c, b1c, F);
  gemm16<256, 1><<<dim3(144, 64), 256, 0, stream>>>(F, W1c, bf1c, nullptr, G, 1024);
  gemm16<1024, 2><<<dim3(144, 16), 256, 0, stream>>>(G, W2c, bf2c, F, Y, 256);
  ln_out_kernel<<<2304, 256, 0, stream>>>(Y, g2c, b2c, d_out, flagp);
}

// Round 5
// 522.083 us; speedup vs baseline: 4.3744x; 4.3744x over previous
//
#include <hip/hip_runtime.h>
#include <hip/hip_bf16.h>
#include <math.h>

typedef __hip_bfloat16 bf16;
typedef __attribute__((ext_vector_type(8))) short short8;
typedef __attribute__((ext_vector_type(4))) short short4v;
typedef __attribute__((ext_vector_type(4))) float f32x4;

#define NSEQ 2304
#define CDIM 256
#define NHD  4
#define DH   64

static __device__ __forceinline__ f32x4 mfma_bf16(short8 a, short8 b, f32x4 c) {
  return __builtin_amdgcn_mfma_f32_16x16x32_bf16(a, b, c, 0, 0, 0);
}
static __device__ __forceinline__ short8 ld8(const bf16* p) {
  return *reinterpret_cast<const short8*>(p);
}
static __device__ __forceinline__ float b2f(short v) {
  unsigned int u = ((unsigned int)(unsigned short)v) << 16;
  return __uint_as_float(u);
}

// ---------------- dtype probe: are float inputs fp32 or bf16? ----------------
__global__ __launch_bounds__(256) void detect_kernel(const void* __restrict__ xraw,
                                                     int* __restrict__ flag) {
  int t = threadIdx.x;
  const unsigned short* s = (const unsigned short*)xraw;
  int bad = 0;
#pragma unroll
  for (int i = 0; i < 8; ++i) {
    unsigned idx = (((unsigned)(t * 8 + i)) * 9173u) & ((1u << 20) - 1);
    unsigned short v = s[idx * 2];
    unsigned e = (v >> 7) & 0xFFu;
    if (e > 133u) bad++;
  }
  __shared__ int tot;
  if (t == 0) tot = 0;
  __syncthreads();
  atomicAdd(&tot, bad);
  __syncthreads();
  if (t == 0) flag[0] = (tot >= 16) ? 1 : 0;
}

// ---------------- convert a float input to a bf16 copy ----------------
__global__ __launch_bounds__(256) void cvt_kernel(const void* __restrict__ src,
                                                  bf16* __restrict__ dst, int n,
                                                  const int* __restrict__ flag) {
  int is32 = flag[0];
  int i = blockIdx.x * 256 + threadIdx.x;
  if (i >= n) return;
  if (is32) dst[i] = __float2bfloat16(((const float*)src)[i]);
  else      dst[i] = ((const bf16*)src)[i];
}

// ---------------- convert the 6 small vectors in one launch ----------------
__global__ __launch_bounds__(256) void cvt_small_kernel(const void* s0, const void* s1, const void* s2,
                                                        const void* s3, const void* s4, const void* s5,
                                                        bf16* d0, bf16* d1, bf16* d2,
                                                        bf16* d3, bf16* d4, bf16* d5,
                                                        const int* __restrict__ flag) {
  int is32 = flag[0];
  int t = threadIdx.x;
  const void* srcs[6] = {s0, s1, s2, s3, s4, s5};
  bf16* dsts[6] = {d0, d1, d2, d3, d4, d5};
  const int ns[6] = {256, 256, 256, 256, 1024, 256};
#pragma unroll
  for (int j = 0; j < 6; ++j) {
    for (int i = t; i < ns[j]; i += 256) {
      if (is32) dsts[j][i] = __float2bfloat16(((const float*)srcs[j])[i]);
      else      dsts[j][i] = ((const bf16*)srcs[j])[i];
    }
  }
}

// ---------------- QKV GEMM: qkv = x @ Wqkv^T, scatter into Q,K,V^T ----------------
__global__ __launch_bounds__(256) void qkv_kernel(const bf16* __restrict__ X,
                                                  const bf16* __restrict__ Wqkv,
                                                  bf16* __restrict__ Q, bf16* __restrict__ K,
                                                  bf16* __restrict__ Vt) {
  int wave = threadIdx.x >> 6, lane = threadIdx.x & 63;
  int l15 = lane & 15, quad = lane >> 4;
  int m0 = (blockIdx.x * 4 + wave) * 16;
  int n0 = blockIdx.y * 16;
  const bf16* arow = X + (size_t)(m0 + l15) * CDIM + quad * 8;
  const bf16* brow = Wqkv + (size_t)(n0 + l15) * CDIM + quad * 8;
  f32x4 acc = {0.f, 0.f, 0.f, 0.f};
#pragma unroll
  for (int kk = 0; kk < CDIM; kk += 32)
    acc = mfma_bf16(ld8(arow + kk), ld8(brow + kk), acc);

  int col = n0 + l15;
  int which = col >> 8, rem = col & 255;
  int h = rem >> 6, d = rem & 63;
#pragma unroll
  for (int r = 0; r < 4; ++r) {
    int gm = m0 + quad * 4 + r;
    int b = gm / NSEQ, n = gm % NSEQ;
    int bh = b * NHD + h;
    bf16 val = __float2bfloat16(acc[r]);
    if (which == 0)      Q[((size_t)bh * NSEQ + n) * DH + d] = val;
    else if (which == 1) K[((size_t)bh * NSEQ + n) * DH + d] = val;
    else                 Vt[((size_t)bh * DH + d) * NSEQ + n] = val;
  }
}

// ---------------- RoPE (2D), in place on Q and K ----------------
__global__ __launch_bounds__(256) void rope_kernel(bf16* __restrict__ Q, bf16* __restrict__ K,
                                                   const int* __restrict__ Wp) {
  int Wv = Wp[0];
  if (Wv <= 0 || Wv > 65536) Wv = 48;
  int t = blockIdx.x * 256 + threadIdx.x;   // 73728 rows * 32 pair-slots
  int p = t & 31;
  int row = t >> 5;
  int which = (row >= 16 * NSEQ) ? 1 : 0;
  int r2 = which ? row - 16 * NSEQ : row;
  int bh = r2 / NSEQ, n = r2 % NSEQ;
  int py = n / Wv, px = n - py * Wv;
  int part = p >> 4, i = p & 15;
  float pos = (float)(part ? px : py);
  int j0 = 2 * i;
  const float c = -9.210340371976184f / 32.0f;  // -ln(10000)/32
  float f0 = expf(c * (float)j0);
  float f1 = expf(c * (float)(j0 + 1));
  float s0, c0, s1, c1;
  sincosf(pos * f0, &s0, &c0);
  sincosf(pos * f1, &s1, &c1);
  bf16* base = (which ? K : Q) + ((size_t)bh * NSEQ + n) * DH + part * 32 + j0;
  float a  = __bfloat162float(base[0]);
  float bb = __bfloat162float(base[1]);
  base[0] = __float2bfloat16(a * c0 - bb * s0);
  base[1] = __float2bfloat16(bb * c1 + a * s1);
}

// ---------------- Flash attention (MFMA): one wave = 16 q rows, 32-key chunks ----------------
__global__ __launch_bounds__(256) void attn_kernel(const bf16* __restrict__ Q, const bf16* __restrict__ K,
                                                   const bf16* __restrict__ Vt, bf16* __restrict__ AO) {
  int bh = blockIdx.x, qt = blockIdx.y;
  int wave = threadIdx.x >> 6, lane = threadIdx.x & 63;
  int l15 = lane & 15, quad = lane >> 4;
  int m0 = qt * 64 + wave * 16;
  const bf16* Qb = Q + (size_t)bh * NSEQ * DH;
  const bf16* Kb = K + (size_t)bh * NSEQ * DH;
  const bf16* Vb = Vt + (size_t)bh * DH * NSEQ;

  short8 aq0 = ld8(Qb + (size_t)(m0 + l15) * DH + quad * 8);
  short8 aq1 = ld8(Qb + (size_t)(m0 + l15) * DH + 32 + quad * 8);

  f32x4 o[4];
  float mrow[4], lrow[4];
  f32x4 z = {0.f, 0.f, 0.f, 0.f};
#pragma unroll
  for (int r = 0; r < 4; ++r) { o[r] = z; mrow[r] = -3e38f; lrow[r] = 0.f; }

  __shared__ __align__(16) bf16 plds[2][4][512];
  const float scale = 0.125f;  // 1/sqrt(64)

  for (int kc = 0, it = 0; kc < NSEQ; kc += 32, ++it) {
    const bf16* k0p = Kb + (size_t)(kc + l15) * DH + quad * 8;
    const bf16* k1p = Kb + (size_t)(kc + 16 + l15) * DH + quad * 8;
    f32x4 s0 = mfma_bf16(aq0, ld8(k0p), z);       s0 = mfma_bf16(aq1, ld8(k0p + 32), s0);
    f32x4 s1 = mfma_bf16(aq0, ld8(k1p), z);       s1 = mfma_bf16(aq1, ld8(k1p + 32), s1);

    bf16* pb = plds[it & 1][wave];
#pragma unroll
    for (int r = 0; r < 4; ++r) {
      float sa = s0[r] * scale, sb = s1[r] * scale;
      float mx = fmaxf(sa, sb);
      mx = fmaxf(mx, __shfl_xor(mx, 1));
      mx = fmaxf(mx, __shfl_xor(mx, 2));
      mx = fmaxf(mx, __shfl_xor(mx, 4));
      mx = fmaxf(mx, __shfl_xor(mx, 8));
      float mnew = fmaxf(mrow[r], mx);
      float ea = __expf(sa - mnew), eb = __expf(sb - mnew);
      float ps = ea + eb;
      ps += __shfl_xor(ps, 1); ps += __shfl_xor(ps, 2);
      ps += __shfl_xor(ps, 4); ps += __shfl_xor(ps, 8);
      float alpha = __expf(mrow[r] - mnew);
      lrow[r] = lrow[r] * alpha + ps;
      mrow[r] = mnew;
#pragma unroll
      for (int nt = 0; nt < 4; ++nt) o[nt][r] *= alpha;
      int m = quad * 4 + r;
      pb[m * 32 + l15]      = __float2bfloat16(ea);
      pb[m * 32 + 16 + l15] = __float2bfloat16(eb);
    }
    __syncthreads();
    short8 pa = ld8(pb + l15 * 32 + quad * 8);
#pragma unroll
    for (int nt = 0; nt < 4; ++nt) {
      short8 bv = ld8(Vb + (size_t)(nt * 16 + l15) * NSEQ + kc + quad * 8);
      o[nt] = mfma_bf16(pa, bv, o[nt]);
    }
  }

  int b = bh >> 2, h = bh & 3;
#pragma unroll
  for (int r = 0; r < 4; ++r) {
    int n = m0 + quad * 4 + r;
    float inv = 1.f / lrow[r];
#pragma unroll
    for (int nt = 0; nt < 4; ++nt) {
      int colc = h * DH + nt * 16 + l15;
      AO[((size_t)b * NSEQ + n) * CDIM + colc] = __float2bfloat16(o[nt][r] * inv);
    }
  }
}

// ---------------- Generic MFMA GEMM  out = A @ Wm^T (+epilogue), bf16 out ----------------
template <int KD, int EPI>
__global__ __launch_bounds__(256) void gemm16(const bf16* __restrict__ A, const bf16* __restrict__ Wm,
                                              const bf16* __restrict__ bias, const bf16* __restrict__ res,
                                              bf16* __restrict__ outp, int NC) {
  int wave = threadIdx.x >> 6, lane = threadIdx.x & 63;
  int l15 = lane & 15, quad = lane >> 4;
  int m0 = (blockIdx.x * 4 + wave) * 16;
  int n0 = blockIdx.y * 16;
  const bf16* arow = A + (size_t)(m0 + l15) * KD + quad * 8;
  const bf16* brow = Wm + (size_t)(n0 + l15) * KD + quad * 8;
  f32x4 acc = {0.f, 0.f, 0.f, 0.f};
#pragma unroll 8
  for (int kk = 0; kk < KD; kk += 32)
    acc = mfma_bf16(ld8(arow + kk), ld8(brow + kk), acc);

  int col = n0 + l15;
#pragma unroll
  for (int r = 0; r < 4; ++r) {
    int gm = m0 + quad * 4 + r;
    size_t idx = (size_t)gm * NC + col;
    if (EPI == 0) {
      outp[idx] = __float2bfloat16(acc[r] + __bfloat162float(res[idx]));
    } else if (EPI == 1) {
      float hv = acc[r] + __bfloat162float(bias[col]);
      float gv = 0.5f * hv * (1.f + erff(hv * 0.70710678118f));
      outp[idx] = __float2bfloat16(gv);
    } else {
      outp[idx] = __float2bfloat16(acc[r] + __bfloat162float(bias[col]) + __bfloat162float(res[idx]));
    }
  }
}

// ---------------- LayerNorm bf16->bf16 (one wave per row) ----------------
__global__ __launch_bounds__(256) void ln_kernel(const bf16* __restrict__ X, const bf16* __restrict__ g,
                                                 const bf16* __restrict__ bv, bf16* __restrict__ out) {
  int row = blockIdx.x * 4 + (threadIdx.x >> 6);
  int lane = threadIdx.x & 63;
  short4v raw = *reinterpret_cast<const short4v*>(X + (size_t)row * CDIM + lane * 4);
  float vv[4];
  float s = 0.f, sq = 0.f;
#pragma unroll
  for (int i = 0; i < 4; ++i) {
    float f = b2f(raw[i]);
    vv[i] = f; s += f; sq += f * f;
  }
#pragma unroll
  for (int off = 1; off < 64; off <<= 1) { s += __shfl_xor(s, off); sq += __shfl_xor(sq, off); }
  float mu = s * (1.f / CDIM);
  float var = sq * (1.f / CDIM) - mu * mu;
  float rstd = rsqrtf(var + 1e-5f);
#pragma unroll
  for (int i = 0; i < 4; ++i) {
    int c = lane * 4 + i;
    out[(size_t)row * CDIM + c] =
        __float2bfloat16((vv[i] - mu) * rstd * __bfloat162float(g[c]) + __bfloat162float(bv[c]));
  }
}

// ---------------- Final LayerNorm: bf16 in, flag-dependent dtype out ----------------
__global__ __launch_bounds__(256) void ln_out_kernel(const bf16* __restrict__ X, const bf16* __restrict__ g,
                                                     const bf16* __restrict__ bv, void* __restrict__ out,
                                                     const int* __restrict__ flag) {
  int is32 = flag[0];
  int row = blockIdx.x * 4 + (threadIdx.x >> 6);
  int lane = threadIdx.x & 63;
  short4v raw = *reinterpret_cast<const short4v*>(X + (size_t)row * CDIM + lane * 4);
  float vv[4];
  float s = 0.f, sq = 0.f;
#pragma unroll
  for (int i = 0; i < 4; ++i) {
    float f = b2f(raw[i]);
    vv[i] = f; s += f; sq += f * f;
  }
#pragma unroll
  for (int off = 1; off < 64; off <<= 1) { s += __shfl_xor(s, off); sq += __shfl_xor(sq, off); }
  float mu = s * (1.f / CDIM);
  float var = sq * (1.f / CDIM) - mu * mu;
  float rstd = rsqrtf(var + 1e-5f);
#pragma unroll
  for (int i = 0; i < 4; ++i) {
    int c = lane * 4 + i;
    size_t idx = (size_t)row * CDIM + c;
    float v = (vv[i] - mu) * rstd * __bfloat162float(g[c]) + __bfloat162float(bv[c]);
    if (is32) ((float*)out)[idx] = v;
    else      ((bf16*)out)[idx] = __float2bfloat16(v);
  }
}

extern "C" void kernel_launch(void* const* d_in, const int* in_sizes, int n_in,
                              void* d_out, int out_size, void* d_ws, size_t ws_size,
                              hipStream_t stream) {
  const int* Wp = (const int*)d_in[12];

  char* ws = (char*)d_ws;
  const size_t SZ = 4718592;  // 2304*4*256 bf16 bytes
  bf16* Qc  = (bf16*)(ws + 0 * SZ);
  bf16* Kc  = (bf16*)(ws + 1 * SZ);
  bf16* Vt  = (bf16*)(ws + 2 * SZ);
  bf16* AO  = (bf16*)(ws + 3 * SZ);
  bf16* F   = (bf16*)(ws + 4 * SZ);
  bf16* Y   = (bf16*)(ws + 5 * SZ);
  bf16* xc  = (bf16*)(ws + 6 * SZ);
  bf16* G   = (bf16*)(ws + 0);              // overlays Qc..AO (4*SZ exactly)
  bf16* Wqkvc  = (bf16*)(ws + 7 * SZ);
  bf16* Wprojc = (bf16*)(ws + 7 * SZ + 393216);
  bf16* W1c    = (bf16*)(ws + 7 * SZ + 524288);
  bf16* W2c    = (bf16*)(ws + 7 * SZ + 1048576);
  bf16* bf1c   = (bf16*)(ws + 7 * SZ + 1572864);
  bf16* g1c    = (bf16*)(ws + 7 * SZ + 1574912);
  bf16* b1c    = (bf16*)(ws + 7 * SZ + 1575424);
  bf16* g2c    = (bf16*)(ws + 7 * SZ + 1575936);
  bf16* b2c    = (bf16*)(ws + 7 * SZ + 1576448);
  bf16* bf2c   = (bf16*)(ws + 7 * SZ + 1576960);
  int*  flagp  = (int*)(ws + 7 * SZ + 1577472);
  bf16* outsc  = (bf16*)d_out;  // bf16 scratch (fits in either dtype's buffer)

  detect_kernel<<<1, 256, 0, stream>>>(d_in[0], flagp);
  cvt_kernel<<<9216, 256, 0, stream>>>(d_in[0], xc, 2359296, flagp);
  cvt_kernel<<<768, 256, 0, stream>>>(d_in[1], Wqkvc, 196608, flagp);
  cvt_kernel<<<256, 256, 0, stream>>>(d_in[2], Wprojc, 65536, flagp);
  cvt_kernel<<<1024, 256, 0, stream>>>(d_in[7], W1c, 262144, flagp);
  cvt_kernel<<<1024, 256, 0, stream>>>(d_in[9], W2c, 262144, flagp);
  cvt_small_kernel<<<1, 256, 0, stream>>>(d_in[3], d_in[4], d_in[5], d_in[6], d_in[8], d_in[10],
                                          g1c, b1c, g2c, b2c, bf1c, bf2c, flagp);

  qkv_kernel<<<dim3(144, 48), 256, 0, stream>>>(xc, Wqkvc, Qc, Kc, Vt);
  rope_kernel<<<9216, 256, 0, stream>>>(Qc, Kc, Wp);
  attn_kernel<<<dim3(16, 36), 256, 0, stream>>>(Qc, Kc, Vt, AO);
  gemm16<256, 0><<<dim3(144, 16), 256, 0, stream>>>(AO, Wprojc, nullptr, xc, outsc, 256);
  ln_kernel<<<2304, 256, 0, stream>>>(outsc, g1c, b1c, F);
  gemm16<256, 1><<<dim3(144, 64), 256, 0, stream>>>(F, W1c, bf1c, nullptr, G, 1024);
  gemm16<1024, 2><<<dim3(144, 16), 256, 0, stream>>>(G, W2c, bf2c, F, Y, 256);
  ln_out_kernel<<<2304, 256, 0, stream>>>(Y, g2c, b2c, d_out, flagp);
}

// Round 7
// 470.581 us; speedup vs baseline: 4.8531x; 1.1094x over previous
//
#include <hip/hip_runtime.h>
#include <hip/hip_bf16.h>
#include <math.h>

typedef __hip_bfloat16 bf16;
typedef __attribute__((ext_vector_type(8))) short short8;
typedef __attribute__((ext_vector_type(4))) short short4v;
typedef __attribute__((ext_vector_type(4))) float f32x4;

#define NSEQ 2304
#define CDIM 256
#define NHD  4
#define DH   64

static __device__ __forceinline__ f32x4 mfma_bf16(short8 a, short8 b, f32x4 c) {
  return __builtin_amdgcn_mfma_f32_16x16x32_bf16(a, b, c, 0, 0, 0);
}
static __device__ __forceinline__ short8 ld8(const bf16* p) {
  return *reinterpret_cast<const short8*>(p);
}
static __device__ __forceinline__ float b2f(short v) {
  unsigned int u = ((unsigned int)(unsigned short)v) << 16;
  return __uint_as_float(u);
}
static __device__ __forceinline__ short f2b(float f) {
  bf16 h = __float2bfloat16(f);
  return *reinterpret_cast<short*>(&h);
}

// ---------------- dtype probe: are float inputs fp32 or bf16? ----------------
__global__ __launch_bounds__(256) void detect_kernel(const void* __restrict__ xraw,
                                                     int* __restrict__ flag) {
  int t = threadIdx.x;
  const unsigned short* s = (const unsigned short*)xraw;
  int bad = 0;
#pragma unroll
  for (int i = 0; i < 8; ++i) {
    unsigned idx = (((unsigned)(t * 8 + i)) * 9173u) & ((1u << 20) - 1);
    unsigned short v = s[idx * 2];
    unsigned e = (v >> 7) & 0xFFu;
    if (e > 133u) bad++;
  }
  __shared__ int tot;
  if (t == 0) tot = 0;
  __syncthreads();
  atomicAdd(&tot, bad);
  __syncthreads();
  if (t == 0) flag[0] = (tot >= 16) ? 1 : 0;
}

// ---------------- convert float input to bf16 copy (4 elems/thread) ----------------
__global__ __launch_bounds__(256) void cvt4_kernel(const void* __restrict__ src,
                                                   bf16* __restrict__ dst, int n4,
                                                   const int* __restrict__ flag) {
  int i = blockIdx.x * 256 + threadIdx.x;
  if (i >= n4) return;
  if (flag[0]) {
    float4 v = ((const float4*)src)[i];
    short4v o;
    o[0] = f2b(v.x); o[1] = f2b(v.y); o[2] = f2b(v.z); o[3] = f2b(v.w);
    ((short4v*)dst)[i] = o;
  } else {
    ((short4v*)dst)[i] = ((const short4v*)src)[i];
  }
}

// ---------------- convert the 6 small vectors in one launch ----------------
__global__ __launch_bounds__(256) void cvt_small_kernel(const void* s0, const void* s1, const void* s2,
                                                        const void* s3, const void* s4, const void* s5,
                                                        bf16* d0, bf16* d1, bf16* d2,
                                                        bf16* d3, bf16* d4, bf16* d5,
                                                        const int* __restrict__ flag) {
  int is32 = flag[0];
  int t = threadIdx.x;
  const void* srcs[6] = {s0, s1, s2, s3, s4, s5};
  bf16* dsts[6] = {d0, d1, d2, d3, d4, d5};
  const int ns[6] = {256, 256, 256, 256, 1024, 256};
#pragma unroll
  for (int j = 0; j < 6; ++j) {
    for (int i = t; i < ns[j]; i += 256) {
      if (is32) dsts[j][i] = __float2bfloat16(((const float*)srcs[j])[i]);
      else      dsts[j][i] = ((const bf16*)srcs[j])[i];
    }
  }
}

// ---------------- QKV GEMM (64x16/wave): qkv = x @ Wqkv^T, scatter to Q,K,V^T ----------------
__global__ __launch_bounds__(256) void qkv_kernel(const bf16* __restrict__ X,
                                                  const bf16* __restrict__ Wqkv,
                                                  bf16* __restrict__ Q, bf16* __restrict__ K,
                                                  bf16* __restrict__ Vt) {
  int wave = threadIdx.x >> 6, lane = threadIdx.x & 63;
  int l15 = lane & 15, quad = lane >> 4;
  int m0 = (blockIdx.x * 4 + wave) * 64;
  int n0 = blockIdx.y * 16;
  const bf16* arow = X + (size_t)(m0 + l15) * CDIM + quad * 8;
  const bf16* brow = Wqkv + (size_t)(n0 + l15) * CDIM + quad * 8;
  f32x4 z = {0.f, 0.f, 0.f, 0.f};
  f32x4 acc[4] = {z, z, z, z};
#pragma unroll
  for (int kk = 0; kk < CDIM; kk += 32) {
    short8 b = ld8(brow + kk);
#pragma unroll
    for (int i = 0; i < 4; ++i)
      acc[i] = mfma_bf16(ld8(arow + (size_t)i * 16 * CDIM + kk), b, acc[i]);
  }
  int col = n0 + l15;
  int which = col >> 8, rem = col & 255;
  int h = rem >> 6, d = rem & 63;
#pragma unroll
  for (int i = 0; i < 4; ++i) {
#pragma unroll
    for (int r = 0; r < 4; ++r) {
      int gm = m0 + i * 16 + quad * 4 + r;
      int b = gm / NSEQ, n = gm % NSEQ;
      int bh = b * NHD + h;
      bf16 val = __float2bfloat16(acc[i][r]);
      if (which == 0)      Q[((size_t)bh * NSEQ + n) * DH + d] = val;
      else if (which == 1) K[((size_t)bh * NSEQ + n) * DH + d] = val;
      else                 Vt[((size_t)bh * DH + d) * NSEQ + n] = val;
    }
  }
}

// ---------------- RoPE (2D), in place on Q and K ----------------
__global__ __launch_bounds__(256) void rope_kernel(bf16* __restrict__ Q, bf16* __restrict__ K,
                                                   const int* __restrict__ Wp) {
  int Wv = Wp[0];
  if (Wv <= 0 || Wv > 65536) Wv = 48;
  int t = blockIdx.x * 256 + threadIdx.x;
  int p = t & 31;
  int row = t >> 5;
  int which = (row >= 16 * NSEQ) ? 1 : 0;
  int r2 = which ? row - 16 * NSEQ : row;
  int bh = r2 / NSEQ, n = r2 % NSEQ;
  int py = n / Wv, px = n - py * Wv;
  int part = p >> 4, i = p & 15;
  float pos = (float)(part ? px : py);
  int j0 = 2 * i;
  const float c = -9.210340371976184f / 32.0f;
  float f0 = expf(c * (float)j0);
  float f1 = expf(c * (float)(j0 + 1));
  float s0, c0, s1, c1;
  sincosf(pos * f0, &s0, &c0);
  sincosf(pos * f1, &s1, &c1);
  bf16* base = (which ? K : Q) + ((size_t)bh * NSEQ + n) * DH + part * 32 + j0;
  float a  = __bfloat162float(base[0]);
  float bb = __bfloat162float(base[1]);
  base[0] = __float2bfloat16(a * c0 - bb * s0);
  base[1] = __float2bfloat16(bb * c1 + a * s1);
}

// ---------------- Flash attention, transposed scores ----------------
// One wave = 16 queries. Per 64-key chunk: S^T = K·Q^T (keys in register dim),
// online softmax with only 2 cross-quad shuffles, P^T via per-wave LDS into
// the PV B-fragment, O accumulated transposed (O^T = V^T·P^T). No barriers.
__global__ __launch_bounds__(256) void attn_kernel(const bf16* __restrict__ Q, const bf16* __restrict__ K,
                                                   const bf16* __restrict__ Vt, bf16* __restrict__ AO) {
  int bh = blockIdx.x, qt = blockIdx.y;
  int wave = threadIdx.x >> 6, lane = threadIdx.x & 63;
  int l15 = lane & 15, quad = lane >> 4;
  int m0 = qt * 64 + wave * 16;
  const bf16* Qb = Q + (size_t)bh * NSEQ * DH;
  const bf16* Kb = K + (size_t)bh * NSEQ * DH;
  const bf16* Vb = Vt + (size_t)bh * DH * NSEQ;

  // Q B-fragment, pre-scaled by 1/sqrt(dh)=0.125 (exact in bf16)
  short8 bq0 = ld8(Qb + (size_t)(m0 + l15) * DH + quad * 8);
  short8 bq1 = ld8(Qb + (size_t)(m0 + l15) * DH + 32 + quad * 8);
#pragma unroll
  for (int i = 0; i < 8; ++i) {
    bq0[i] = f2b(b2f(bq0[i]) * 0.125f);
    bq1[i] = f2b(b2f(bq1[i]) * 0.125f);
  }

  f32x4 z = {0.f, 0.f, 0.f, 0.f};
  f32x4 o[4] = {z, z, z, z};
  float m_run = -1e30f, l_run = 0.f;

  __shared__ __align__(16) bf16 plds[4][16 * 72];  // per-wave P^T [q][key], stride 72
  bf16* pb = plds[wave];

  for (int kc = 0; kc < NSEQ; kc += 64) {
    // S^T: 4 key-subtiles of 16; D[key=quad*4+r][q=l15]
    f32x4 s[4];
#pragma unroll
    for (int kt = 0; kt < 4; ++kt) {
      const bf16* kp = Kb + (size_t)(kc + kt * 16 + l15) * DH + quad * 8;
      s[kt] = mfma_bf16(ld8(kp), bq0, z);
      s[kt] = mfma_bf16(ld8(kp + 32), bq1, s[kt]);
    }
    // per-lane max over 16 scores, then cross-quad (2 shuffles)
    float mx = s[0][0];
#pragma unroll
    for (int kt = 0; kt < 4; ++kt)
#pragma unroll
      for (int r = 0; r < 4; ++r) mx = fmaxf(mx, s[kt][r]);
    mx = fmaxf(mx, __shfl_xor(mx, 16));
    mx = fmaxf(mx, __shfl_xor(mx, 32));
    float m_new = fmaxf(m_run, mx);
    float alpha = __expf(m_run - m_new);
    m_run = m_new;

    float ls = 0.f;
#pragma unroll
    for (int kt = 0; kt < 4; ++kt) {
      float p0 = __expf(s[kt][0] - m_new);
      float p1 = __expf(s[kt][1] - m_new);
      float p2 = __expf(s[kt][2] - m_new);
      float p3 = __expf(s[kt][3] - m_new);
      ls += (p0 + p1) + (p2 + p3);
      short4v pk;
      pk[0] = f2b(p0); pk[1] = f2b(p1); pk[2] = f2b(p2); pk[3] = f2b(p3);
      *reinterpret_cast<short4v*>(pb + l15 * 72 + kt * 16 + quad * 4) = pk;
    }
    l_run = l_run * alpha + ls;
#pragma unroll
    for (int t = 0; t < 4; ++t)
#pragma unroll
      for (int r = 0; r < 4; ++r) o[t][r] *= alpha;

    // PV: O^T += V^T · P^T  (B-frag from LDS shared across the 4 dh-tiles)
#pragma unroll
    for (int kt2 = 0; kt2 < 2; ++kt2) {
      short8 pfrag = *reinterpret_cast<const short8*>(pb + l15 * 72 + kt2 * 32 + quad * 8);
#pragma unroll
      for (int t = 0; t < 4; ++t) {
        short8 av = ld8(Vb + (size_t)(t * 16 + l15) * NSEQ + kc + kt2 * 32 + quad * 8);
        o[t] = mfma_bf16(av, pfrag, o[t]);
      }
    }
  }

  // combine l partials across quads; normalize; write O (dh runs of 4 -> b64)
  l_run += __shfl_xor(l_run, 16);
  l_run += __shfl_xor(l_run, 32);
  float inv = 1.f / l_run;
  int b = bh >> 2, h = bh & 3;
  bf16* orow = AO + ((size_t)b * NSEQ + (m0 + l15)) * CDIM + h * DH;
#pragma unroll
  for (int t = 0; t < 4; ++t) {
    short4v ov;
#pragma unroll
    for (int r = 0; r < 4; ++r) ov[r] = f2b(o[t][r] * inv);
    *reinterpret_cast<short4v*>(orow + t * 16 + quad * 4) = ov;
  }
}

// ---------------- Generic MFMA GEMM (64x16/wave)  out = A @ Wm^T (+epilogue) ----------------
// EPI 0: out = acc + res;  EPI 1: out = gelu(acc+bias);  EPI 2: out = acc + bias + res
template <int KD, int EPI>
__global__ __launch_bounds__(256) void gemm64(const bf16* __restrict__ A, const bf16* __restrict__ Wm,
                                              const bf16* __restrict__ bias, const bf16* __restrict__ res,
                                              bf16* __restrict__ outp, int NC) {
  int wave = threadIdx.x >> 6, lane = threadIdx.x & 63;
  int l15 = lane & 15, quad = lane >> 4;
  int m0 = (blockIdx.x * 4 + wave) * 64;
  int n0 = blockIdx.y * 16;
  const bf16* arow = A + (size_t)(m0 + l15) * KD + quad * 8;
  const bf16* brow = Wm + (size_t)(n0 + l15) * KD + quad * 8;
  f32x4 z = {0.f, 0.f, 0.f, 0.f};
  f32x4 acc[4] = {z, z, z, z};
#pragma unroll 4
  for (int kk = 0; kk < KD; kk += 32) {
    short8 b = ld8(brow + kk);
#pragma unroll
    for (int i = 0; i < 4; ++i)
      acc[i] = mfma_bf16(ld8(arow + (size_t)i * 16 * KD + kk), b, acc[i]);
  }
  int col = n0 + l15;
#pragma unroll
  for (int i = 0; i < 4; ++i) {
#pragma unroll
    for (int r = 0; r < 4; ++r) {
      int gm = m0 + i * 16 + quad * 4 + r;
      size_t idx = (size_t)gm * NC + col;
      if (EPI == 0) {
        outp[idx] = __float2bfloat16(acc[i][r] + __bfloat162float(res[idx]));
      } else if (EPI == 1) {
        float hv = acc[i][r] + __bfloat162float(bias[col]);
        float gv = 0.5f * hv * (1.f + erff(hv * 0.70710678118f));
        outp[idx] = __float2bfloat16(gv);
      } else {
        outp[idx] = __float2bfloat16(acc[i][r] + __bfloat162float(bias[col]) + __bfloat162float(res[idx]));
      }
    }
  }
}

// ---------------- LayerNorm bf16->bf16 (one wave per row) ----------------
__global__ __launch_bounds__(256) void ln_kernel(const bf16* __restrict__ X, const bf16* __restrict__ g,
                                                 const bf16* __restrict__ bv, bf16* __restrict__ out) {
  int row = blockIdx.x * 4 + (threadIdx.x >> 6);
  int lane = threadIdx.x & 63;
  short4v raw = *reinterpret_cast<const short4v*>(X + (size_t)row * CDIM + lane * 4);
  float vv[4];
  float s = 0.f, sq = 0.f;
#pragma unroll
  for (int i = 0; i < 4; ++i) {
    float f = b2f(raw[i]);
    vv[i] = f; s += f; sq += f * f;
  }
#pragma unroll
  for (int off = 1; off < 64; off <<= 1) { s += __shfl_xor(s, off); sq += __shfl_xor(sq, off); }
  float mu = s * (1.f / CDIM);
  float var = sq * (1.f / CDIM) - mu * mu;
  float rstd = rsqrtf(var + 1e-5f);
#pragma unroll
  for (int i = 0; i < 4; ++i) {
    int c = lane * 4 + i;
    out[(size_t)row * CDIM + c] =
        __float2bfloat16((vv[i] - mu) * rstd * __bfloat162float(g[c]) + __bfloat162float(bv[c]));
  }
}

// ---------------- Final LayerNorm: bf16 in, flag-dependent dtype out ----------------
__global__ __launch_bounds__(256) void ln_out_kernel(const bf16* __restrict__ X, const bf16* __restrict__ g,
                                                     const bf16* __restrict__ bv, void* __restrict__ out,
                                                     const int* __restrict__ flag) {
  int is32 = flag[0];
  int row = blockIdx.x * 4 + (threadIdx.x >> 6);
  int lane = threadIdx.x & 63;
  short4v raw = *reinterpret_cast<const short4v*>(X + (size_t)row * CDIM + lane * 4);
  float vv[4];
  float s = 0.f, sq = 0.f;
#pragma unroll
  for (int i = 0; i < 4; ++i) {
    float f = b2f(raw[i]);
    vv[i] = f; s += f; sq += f * f;
  }
#pragma unroll
  for (int off = 1; off < 64; off <<= 1) { s += __shfl_xor(s, off); sq += __shfl_xor(sq, off); }
  float mu = s * (1.f / CDIM);
  float var = sq * (1.f / CDIM) - mu * mu;
  float rstd = rsqrtf(var + 1e-5f);
#pragma unroll
  for (int i = 0; i < 4; ++i) {
    int c = lane * 4 + i;
    size_t idx = (size_t)row * CDIM + c;
    float v = (vv[i] - mu) * rstd * __bfloat162float(g[c]) + __bfloat162float(bv[c]);
    if (is32) ((float*)out)[idx] = v;
    else      ((bf16*)out)[idx] = __float2bfloat16(v);
  }
}

extern "C" void kernel_launch(void* const* d_in, const int* in_sizes, int n_in,
                              void* d_out, int out_size, void* d_ws, size_t ws_size,
                              hipStream_t stream) {
  const int* Wp = (const int*)d_in[12];

  char* ws = (char*)d_ws;
  const size_t SZ = 4718592;  // 2304*4*256 bf16 bytes
  bf16* Qc  = (bf16*)(ws + 0 * SZ);
  bf16* Kc  = (bf16*)(ws + 1 * SZ);
  bf16* Vt  = (bf16*)(ws + 2 * SZ);
  bf16* AO  = (bf16*)(ws + 3 * SZ);
  bf16* F   = (bf16*)(ws + 4 * SZ);
  bf16* Y   = (bf16*)(ws + 5 * SZ);
  bf16* xc  = (bf16*)(ws + 6 * SZ);
  bf16* G   = (bf16*)(ws + 0);              // overlays Qc..AO (4*SZ exactly)
  bf16* Wqkvc  = (bf16*)(ws + 7 * SZ);
  bf16* Wprojc = (bf16*)(ws + 7 * SZ + 393216);
  bf16* W1c    = (bf16*)(ws + 7 * SZ + 524288);
  bf16* W2c    = (bf16*)(ws + 7 * SZ + 1048576);
  bf16* bf1c   = (bf16*)(ws + 7 * SZ + 1572864);
  bf16* g1c    = (bf16*)(ws + 7 * SZ + 1574912);
  bf16* b1c    = (bf16*)(ws + 7 * SZ + 1575424);
  bf16* g2c    = (bf16*)(ws + 7 * SZ + 1575936);
  bf16* b2c    = (bf16*)(ws + 7 * SZ + 1576448);
  bf16* bf2c   = (bf16*)(ws + 7 * SZ + 1576960);
  int*  flagp  = (int*)(ws + 7 * SZ + 1577472);
  bf16* outsc  = (bf16*)d_out;  // bf16 scratch (fits in either dtype's buffer)

  detect_kernel<<<1, 256, 0, stream>>>(d_in[0], flagp);
  cvt4_kernel<<<2304, 256, 0, stream>>>(d_in[0], xc, 589824, flagp);
  cvt4_kernel<<<192, 256, 0, stream>>>(d_in[1], Wqkvc, 49152, flagp);
  cvt4_kernel<<<64, 256, 0, stream>>>(d_in[2], Wprojc, 16384, flagp);
  cvt4_kernel<<<256, 256, 0, stream>>>(d_in[7], W1c, 65536, flagp);
  cvt4_kernel<<<256, 256, 0, stream>>>(d_in[9], W2c, 65536, flagp);
  cvt_small_kernel<<<1, 256, 0, stream>>>(d_in[3], d_in[4], d_in[5], d_in[6], d_in[8], d_in[10],
                                          g1c, b1c, g2c, b2c, bf1c, bf2c, flagp);

  qkv_kernel<<<dim3(36, 48), 256, 0, stream>>>(xc, Wqkvc, Qc, Kc, Vt);
  rope_kernel<<<9216, 256, 0, stream>>>(Qc, Kc, Wp);
  attn_kernel<<<dim3(16, 36), 256, 0, stream>>>(Qc, Kc, Vt, AO);
  gemm64<256, 0><<<dim3(36, 16), 256, 0, stream>>>(AO, Wprojc, nullptr, xc, outsc, 256);
  ln_kernel<<<2304, 256, 0, stream>>>(outsc, g1c, b1c, F);
  gemm64<256, 1><<<dim3(36, 64), 256, 0, stream>>>(F, W1c, bf1c, nullptr, G, 1024);
  gemm64<1024, 2><<<dim3(36, 16), 256, 0, stream>>>(G, W2c, bf2c, F, Y, 256);
  ln_out_kernel<<<2304, 256, 0, stream>>>(Y, g2c, b2c, d_out, flagp);
}

// Round 8
// 418.067 us; speedup vs baseline: 5.4627x; 1.1256x over previous
//
#include <hip/hip_runtime.h>
#include <hip/hip_bf16.h>
#include <math.h>

typedef __hip_bfloat16 bf16;
typedef __attribute__((ext_vector_type(8))) short short8;
typedef __attribute__((ext_vector_type(4))) short short4v;
typedef __attribute__((ext_vector_type(4))) float f32x4;

#define NSEQ 2304
#define CDIM 256
#define NHD  4
#define DH   64

static __device__ __forceinline__ f32x4 mfma_bf16(short8 a, short8 b, f32x4 c) {
  return __builtin_amdgcn_mfma_f32_16x16x32_bf16(a, b, c, 0, 0, 0);
}
static __device__ __forceinline__ short8 ld8(const bf16* p) {
  return *reinterpret_cast<const short8*>(p);
}
static __device__ __forceinline__ float b2f(short v) {
  unsigned int u = ((unsigned int)(unsigned short)v) << 16;
  return __uint_as_float(u);
}
static __device__ __forceinline__ short f2b(float f) {
  bf16 h = __float2bfloat16(f);
  return *reinterpret_cast<short*>(&h);
}

// ---------------- dtype probe: are float inputs fp32 or bf16? ----------------
__global__ __launch_bounds__(256) void detect_kernel(const void* __restrict__ xraw,
                                                     int* __restrict__ flag) {
  int t = threadIdx.x;
  const unsigned short* s = (const unsigned short*)xraw;
  int bad = 0;
#pragma unroll
  for (int i = 0; i < 8; ++i) {
    unsigned idx = (((unsigned)(t * 8 + i)) * 9173u) & ((1u << 20) - 1);
    unsigned short v = s[idx * 2];
    unsigned e = (v >> 7) & 0xFFu;
    if (e > 133u) bad++;
  }
  __shared__ int tot;
  if (t == 0) tot = 0;
  __syncthreads();
  atomicAdd(&tot, bad);
  __syncthreads();
  if (t == 0) flag[0] = (tot >= 16) ? 1 : 0;
}

// ---------------- one fused conversion kernel for ALL float inputs ----------------
__global__ __launch_bounds__(256) void cvt_all_kernel(const void* sx, const void* sqkv, const void* sproj,
                                                      const void* sw1, const void* sw2,
                                                      const void* g1, const void* b1, const void* g2,
                                                      const void* b2, const void* bias1, const void* bias2,
                                                      bf16* dx, bf16* dqkv, bf16* dproj,
                                                      bf16* dw1, bf16* dw2, bf16* dsm,
                                                      const int* __restrict__ flag) {
  int is32 = flag[0];
  int bid = blockIdx.x;
  const void* src; bf16* dst; int i4;
  if (bid < 2304)      { src = sx;    dst = dx;    i4 = bid * 256 + threadIdx.x; }
  else if (bid < 2496) { src = sqkv;  dst = dqkv;  i4 = (bid - 2304) * 256 + threadIdx.x; }
  else if (bid < 2560) { src = sproj; dst = dproj; i4 = (bid - 2496) * 256 + threadIdx.x; }
  else if (bid < 2816) { src = sw1;   dst = dw1;   i4 = (bid - 2560) * 256 + threadIdx.x; }
  else if (bid < 3072) { src = sw2;   dst = dw2;   i4 = (bid - 2816) * 256 + threadIdx.x; }
  else {
    // small vectors: packed into dsm: [g1(256) b1(256) g2(256) b2(256) bf1(1024) bf2(256)]
    const void* srcs[6] = {g1, b1, g2, b2, bias1, bias2};
    const int ns[6] = {256, 256, 256, 256, 1024, 256};
    const int off[6] = {0, 256, 512, 768, 1024, 2048};
    int t = threadIdx.x;
#pragma unroll
    for (int j = 0; j < 6; ++j)
      for (int i = t; i < ns[j]; i += 256) {
        if (is32) dsm[off[j] + i] = __float2bfloat16(((const float*)srcs[j])[i]);
        else      dsm[off[j] + i] = ((const bf16*)srcs[j])[i];
      }
    return;
  }
  if (is32) {
    float4 v = ((const float4*)src)[i4];
    short4v o;
    o[0] = f2b(v.x); o[1] = f2b(v.y); o[2] = f2b(v.z); o[3] = f2b(v.w);
    ((short4v*)dst)[i4] = o;
  } else {
    ((short4v*)dst)[i4] = ((const short4v*)src)[i4];
  }
}

// ---------------- QKV GEMM, transposed-acc tiles, prefetch pipeline ----------------
// Block: 4 waves x (64 rows x 64 cols). Wave: 4 M-tiles x 4 N-tiles, acc^T.
__global__ __launch_bounds__(256) void qkv_kernel(const bf16* __restrict__ X,
                                                  const bf16* __restrict__ Wqkv,
                                                  bf16* __restrict__ Q, bf16* __restrict__ K,
                                                  bf16* __restrict__ Vt) {
  int wave = threadIdx.x >> 6, lane = threadIdx.x & 63;
  int l15 = lane & 15, quad = lane >> 4;
  int m0 = (blockIdx.x * 4 + wave) * 64;
  int n0 = blockIdx.y * 64;
  const bf16* arow = X + (size_t)(m0 + l15) * CDIM + quad * 8;     // B-operand (act rows)
  const bf16* brow = Wqkv + (size_t)(n0 + l15) * CDIM + quad * 8;  // A-operand (weight cols)
  f32x4 z = {0.f, 0.f, 0.f, 0.f};
  f32x4 acc[4][4];  // [j: N-tile][i: M-tile]
#pragma unroll
  for (int j = 0; j < 4; ++j)
#pragma unroll
    for (int i = 0; i < 4; ++i) acc[j][i] = z;

  short8 a[4], b[4];
#pragma unroll
  for (int i = 0; i < 4; ++i) a[i] = ld8(arow + (size_t)i * 16 * CDIM);
#pragma unroll
  for (int j = 0; j < 4; ++j) b[j] = ld8(brow + (size_t)j * 16 * CDIM);
#pragma unroll
  for (int kk = 32; kk <= CDIM; kk += 32) {
    short8 an[4], bn[4];
    if (kk < CDIM) {
#pragma unroll
      for (int i = 0; i < 4; ++i) an[i] = ld8(arow + (size_t)i * 16 * CDIM + kk);
#pragma unroll
      for (int j = 0; j < 4; ++j) bn[j] = ld8(brow + (size_t)j * 16 * CDIM + kk);
    }
#pragma unroll
    for (int j = 0; j < 4; ++j)
#pragma unroll
      for (int i = 0; i < 4; ++i) acc[j][i] = mfma_bf16(b[j], a[i], acc[j][i]);
    if (kk < CDIM) {
#pragma unroll
      for (int i = 0; i < 4; ++i) a[i] = an[i];
#pragma unroll
      for (int j = 0; j < 4; ++j) b[j] = bn[j];
    }
  }

  // which/h constant per wave (n0 is 64-aligned)
  int which = n0 >> 8, h = (n0 & 255) >> 6;
#pragma unroll
  for (int j = 0; j < 4; ++j) {
    int d0 = j * 16 + quad * 4;
#pragma unroll
    for (int i = 0; i < 4; ++i) {
      int gm = m0 + i * 16 + l15;
      int bb = gm / NSEQ, n = gm % NSEQ;
      int bh = bb * NHD + h;
      short4v ov;
#pragma unroll
      for (int r = 0; r < 4; ++r) ov[r] = f2b(acc[j][i][r]);
      if (which == 0)
        *reinterpret_cast<short4v*>(Q + ((size_t)bh * NSEQ + n) * DH + d0) = ov;
      else if (which == 1)
        *reinterpret_cast<short4v*>(K + ((size_t)bh * NSEQ + n) * DH + d0) = ov;
      else {
#pragma unroll
        for (int r = 0; r < 4; ++r)
          Vt[((size_t)bh * DH + d0 + r) * NSEQ + n] = __float2bfloat16(acc[j][i][r]);
      }
    }
  }
}

// ---------------- RoPE (2D), in place on Q and K ----------------
__global__ __launch_bounds__(256) void rope_kernel(bf16* __restrict__ Q, bf16* __restrict__ K,
                                                   const int* __restrict__ Wp) {
  int Wv = Wp[0];
  if (Wv <= 0 || Wv > 65536) Wv = 48;
  int t = blockIdx.x * 256 + threadIdx.x;
  int p = t & 31;
  int row = t >> 5;
  int which = (row >= 16 * NSEQ) ? 1 : 0;
  int r2 = which ? row - 16 * NSEQ : row;
  int bh = r2 / NSEQ, n = r2 % NSEQ;
  int py = n / Wv, px = n - py * Wv;
  int part = p >> 4, i = p & 15;
  float pos = (float)(part ? px : py);
  int j0 = 2 * i;
  const float c = -9.210340371976184f / 32.0f;
  float f0 = expf(c * (float)j0);
  float f1 = expf(c * (float)(j0 + 1));
  float s0, c0, s1, c1;
  sincosf(pos * f0, &s0, &c0);
  sincosf(pos * f1, &s1, &c1);
  bf16* base = (which ? K : Q) + ((size_t)bh * NSEQ + n) * DH + part * 32 + j0;
  float a  = __bfloat162float(base[0]);
  float bb = __bfloat162float(base[1]);
  base[0] = __float2bfloat16(a * c0 - bb * s0);
  base[1] = __float2bfloat16(bb * c1 + a * s1);
}

// ---------------- Flash attention, transposed scores + register prefetch ----------------
__global__ __launch_bounds__(256) void attn_kernel(const bf16* __restrict__ Q, const bf16* __restrict__ K,
                                                   const bf16* __restrict__ Vt, bf16* __restrict__ AO) {
  int bh = blockIdx.x, qt = blockIdx.y;
  int wave = threadIdx.x >> 6, lane = threadIdx.x & 63;
  int l15 = lane & 15, quad = lane >> 4;
  int m0 = qt * 64 + wave * 16;
  const bf16* Qb = Q + (size_t)bh * NSEQ * DH;
  const bf16* Kb = K + (size_t)bh * NSEQ * DH;
  const bf16* Vb = Vt + (size_t)bh * DH * NSEQ;

  short8 bq0 = ld8(Qb + (size_t)(m0 + l15) * DH + quad * 8);
  short8 bq1 = ld8(Qb + (size_t)(m0 + l15) * DH + 32 + quad * 8);
#pragma unroll
  for (int i = 0; i < 8; ++i) {
    bq0[i] = f2b(b2f(bq0[i]) * 0.125f);
    bq1[i] = f2b(b2f(bq1[i]) * 0.125f);
  }

  f32x4 z = {0.f, 0.f, 0.f, 0.f};
  f32x4 o[4] = {z, z, z, z};
  float m_run = -1e30f, l_run = 0.f;

  __shared__ __align__(16) bf16 plds[4][16 * 72];
  bf16* pb = plds[wave];

  // prefetch K fragments for kc = 0
  short8 kf0[4], kf1[4];
#pragma unroll
  for (int kt = 0; kt < 4; ++kt) {
    const bf16* kp = Kb + (size_t)(kt * 16 + l15) * DH + quad * 8;
    kf0[kt] = ld8(kp);
    kf1[kt] = ld8(kp + 32);
  }

  for (int kc = 0; kc < NSEQ; kc += 64) {
    // V fragments for this chunk (needed late -> issue first)
    short8 vf[4][2];
#pragma unroll
    for (int kt2 = 0; kt2 < 2; ++kt2)
#pragma unroll
      for (int t = 0; t < 4; ++t)
        vf[t][kt2] = ld8(Vb + (size_t)(t * 16 + l15) * NSEQ + kc + kt2 * 32 + quad * 8);
    // prefetch next chunk's K
    short8 kn0[4], kn1[4];
    bool more = (kc + 64 < NSEQ);
    if (more) {
#pragma unroll
      for (int kt = 0; kt < 4; ++kt) {
        const bf16* kp = Kb + (size_t)(kc + 64 + kt * 16 + l15) * DH + quad * 8;
        kn0[kt] = ld8(kp);
        kn1[kt] = ld8(kp + 32);
      }
    }

    // S^T from prefetched registers
    f32x4 s[4];
#pragma unroll
    for (int kt = 0; kt < 4; ++kt) {
      s[kt] = mfma_bf16(kf0[kt], bq0, z);
      s[kt] = mfma_bf16(kf1[kt], bq1, s[kt]);
    }
    float mx = s[0][0];
#pragma unroll
    for (int kt = 0; kt < 4; ++kt)
#pragma unroll
      for (int r = 0; r < 4; ++r) mx = fmaxf(mx, s[kt][r]);
    mx = fmaxf(mx, __shfl_xor(mx, 16));
    mx = fmaxf(mx, __shfl_xor(mx, 32));
    float m_new = fmaxf(m_run, mx);
    float alpha = __expf(m_run - m_new);
    m_run = m_new;

    float ls = 0.f;
#pragma unroll
    for (int kt = 0; kt < 4; ++kt) {
      float p0 = __expf(s[kt][0] - m_new);
      float p1 = __expf(s[kt][1] - m_new);
      float p2 = __expf(s[kt][2] - m_new);
      float p3 = __expf(s[kt][3] - m_new);
      ls += (p0 + p1) + (p2 + p3);
      short4v pk;
      pk[0] = f2b(p0); pk[1] = f2b(p1); pk[2] = f2b(p2); pk[3] = f2b(p3);
      *reinterpret_cast<short4v*>(pb + l15 * 72 + kt * 16 + quad * 4) = pk;
    }
    l_run = l_run * alpha + ls;
#pragma unroll
    for (int t = 0; t < 4; ++t)
#pragma unroll
      for (int r = 0; r < 4; ++r) o[t][r] *= alpha;

#pragma unroll
    for (int kt2 = 0; kt2 < 2; ++kt2) {
      short8 pfrag = *reinterpret_cast<const short8*>(pb + l15 * 72 + kt2 * 32 + quad * 8);
#pragma unroll
      for (int t = 0; t < 4; ++t)
        o[t] = mfma_bf16(vf[t][kt2], pfrag, o[t]);
    }
    if (more) {
#pragma unroll
      for (int kt = 0; kt < 4; ++kt) { kf0[kt] = kn0[kt]; kf1[kt] = kn1[kt]; }
    }
  }

  l_run += __shfl_xor(l_run, 16);
  l_run += __shfl_xor(l_run, 32);
  float inv = 1.f / l_run;
  int b = bh >> 2, h = bh & 3;
  bf16* orow = AO + ((size_t)b * NSEQ + (m0 + l15)) * CDIM + h * DH;
#pragma unroll
  for (int t = 0; t < 4; ++t) {
    short4v ov;
#pragma unroll
    for (int r = 0; r < 4; ++r) ov[r] = f2b(o[t][r] * inv);
    *reinterpret_cast<short4v*>(orow + t * 16 + quad * 4) = ov;
  }
}

// ---------------- GEMM, transposed-acc tiles, prefetch pipeline ----------------
// Wave: TI M-tiles x 4 N-tiles (64 cols). Block: 4 waves stacked in M.
// EPI 0: out = acc + res;  EPI 1: out = gelu(acc+bias);  EPI 2: out = acc + bias + res
template <int KD, int EPI, int TI>
__global__ __launch_bounds__(256) void gemmT(const bf16* __restrict__ A, const bf16* __restrict__ Wm,
                                             const bf16* __restrict__ bias, const bf16* __restrict__ res,
                                             bf16* __restrict__ outp, int NC) {
  int wave = threadIdx.x >> 6, lane = threadIdx.x & 63;
  int l15 = lane & 15, quad = lane >> 4;
  int m0 = (blockIdx.x * 4 + wave) * (16 * TI);
  int n0 = blockIdx.y * 64;
  const bf16* arow = A + (size_t)(m0 + l15) * KD + quad * 8;
  const bf16* brow = Wm + (size_t)(n0 + l15) * KD + quad * 8;
  f32x4 z = {0.f, 0.f, 0.f, 0.f};
  f32x4 acc[4][TI];
#pragma unroll
  for (int j = 0; j < 4; ++j)
#pragma unroll
    for (int i = 0; i < TI; ++i) acc[j][i] = z;

  short8 a[TI], b[4];
#pragma unroll
  for (int i = 0; i < TI; ++i) a[i] = ld8(arow + (size_t)i * 16 * KD);
#pragma unroll
  for (int j = 0; j < 4; ++j) b[j] = ld8(brow + (size_t)j * 16 * KD);
#pragma unroll
  for (int kk = 32; kk <= KD; kk += 32) {
    short8 an[TI], bn[4];
    if (kk < KD) {
#pragma unroll
      for (int i = 0; i < TI; ++i) an[i] = ld8(arow + (size_t)i * 16 * KD + kk);
#pragma unroll
      for (int j = 0; j < 4; ++j) bn[j] = ld8(brow + (size_t)j * 16 * KD + kk);
    }
#pragma unroll
    for (int j = 0; j < 4; ++j)
#pragma unroll
      for (int i = 0; i < TI; ++i) acc[j][i] = mfma_bf16(b[j], a[i], acc[j][i]);
    if (kk < KD) {
#pragma unroll
      for (int i = 0; i < TI; ++i) a[i] = an[i];
#pragma unroll
      for (int j = 0; j < 4; ++j) b[j] = bn[j];
    }
  }

#pragma unroll
  for (int j = 0; j < 4; ++j) {
    int col0 = n0 + j * 16 + quad * 4;
    float bb4[4];
    if (EPI != 0) {
      short4v bl = *reinterpret_cast<const short4v*>(bias + col0);
#pragma unroll
      for (int r = 0; r < 4; ++r) bb4[r] = b2f(bl[r]);
    }
#pragma unroll
    for (int i = 0; i < TI; ++i) {
      size_t idx = (size_t)(m0 + i * 16 + l15) * NC + col0;
      short4v ov;
      if (EPI == 0) {
        short4v rl = *reinterpret_cast<const short4v*>(res + idx);
#pragma unroll
        for (int r = 0; r < 4; ++r) ov[r] = f2b(acc[j][i][r] + b2f(rl[r]));
      } else if (EPI == 1) {
#pragma unroll
        for (int r = 0; r < 4; ++r) {
          float hv = acc[j][i][r] + bb4[r];
          ov[r] = f2b(0.5f * hv * (1.f + erff(hv * 0.70710678118f)));
        }
      } else {
        short4v rl = *reinterpret_cast<const short4v*>(res + idx);
#pragma unroll
        for (int r = 0; r < 4; ++r) ov[r] = f2b(acc[j][i][r] + bb4[r] + b2f(rl[r]));
      }
      *reinterpret_cast<short4v*>(outp + idx) = ov;
    }
  }
}

// ---------------- LayerNorm bf16->bf16 (one wave per row) ----------------
__global__ __launch_bounds__(256) void ln_kernel(const bf16* __restrict__ X, const bf16* __restrict__ g,
                                                 const bf16* __restrict__ bv, bf16* __restrict__ out) {
  int row = blockIdx.x * 4 + (threadIdx.x >> 6);
  int lane = threadIdx.x & 63;
  short4v raw = *reinterpret_cast<const short4v*>(X + (size_t)row * CDIM + lane * 4);
  float vv[4];
  float s = 0.f, sq = 0.f;
#pragma unroll
  for (int i = 0; i < 4; ++i) {
    float f = b2f(raw[i]);
    vv[i] = f; s += f; sq += f * f;
  }
#pragma unroll
  for (int off = 1; off < 64; off <<= 1) { s += __shfl_xor(s, off); sq += __shfl_xor(sq, off); }
  float mu = s * (1.f / CDIM);
  float var = sq * (1.f / CDIM) - mu * mu;
  float rstd = rsqrtf(var + 1e-5f);
#pragma unroll
  for (int i = 0; i < 4; ++i) {
    int c = lane * 4 + i;
    out[(size_t)row * CDIM + c] =
        __float2bfloat16((vv[i] - mu) * rstd * __bfloat162float(g[c]) + __bfloat162float(bv[c]));
  }
}

// ---------------- Final LayerNorm: bf16 in, flag-dependent dtype out ----------------
__global__ __launch_bounds__(256) void ln_out_kernel(const bf16* __restrict__ X, const bf16* __restrict__ g,
                                                     const bf16* __restrict__ bv, void* __restrict__ out,
                                                     const int* __restrict__ flag) {
  int is32 = flag[0];
  int row = blockIdx.x * 4 + (threadIdx.x >> 6);
  int lane = threadIdx.x & 63;
  short4v raw = *reinterpret_cast<const short4v*>(X + (size_t)row * CDIM + lane * 4);
  float vv[4];
  float s = 0.f, sq = 0.f;
#pragma unroll
  for (int i = 0; i < 4; ++i) {
    float f = b2f(raw[i]);
    vv[i] = f; s += f; sq += f * f;
  }
#pragma unroll
  for (int off = 1; off < 64; off <<= 1) { s += __shfl_xor(s, off); sq += __shfl_xor(sq, off); }
  float mu = s * (1.f / CDIM);
  float var = sq * (1.f / CDIM) - mu * mu;
  float rstd = rsqrtf(var + 1e-5f);
#pragma unroll
  for (int i = 0; i < 4; ++i) {
    int c = lane * 4 + i;
    size_t idx = (size_t)row * CDIM + c;
    float v = (vv[i] - mu) * rstd * __bfloat162float(g[c]) + __bfloat162float(bv[c]);
    if (is32) ((float*)out)[idx] = v;
    else      ((bf16*)out)[idx] = __float2bfloat16(v);
  }
}

extern "C" void kernel_launch(void* const* d_in, const int* in_sizes, int n_in,
                              void* d_out, int out_size, void* d_ws, size_t ws_size,
                              hipStream_t stream) {
  const int* Wp = (const int*)d_in[12];

  char* ws = (char*)d_ws;
  const size_t SZ = 4718592;  // 2304*4*256 bf16 bytes
  bf16* Qc  = (bf16*)(ws + 0 * SZ);
  bf16* Kc  = (bf16*)(ws + 1 * SZ);
  bf16* Vt  = (bf16*)(ws + 2 * SZ);
  bf16* AO  = (bf16*)(ws + 3 * SZ);
  bf16* F   = (bf16*)(ws + 4 * SZ);
  bf16* Y   = (bf16*)(ws + 5 * SZ);
  bf16* xc  = (bf16*)(ws + 6 * SZ);
  bf16* G   = (bf16*)(ws + 0);              // overlays Qc..AO (4*SZ exactly)
  bf16* Wqkvc  = (bf16*)(ws + 7 * SZ);
  bf16* Wprojc = (bf16*)(ws + 7 * SZ + 393216);
  bf16* W1c    = (bf16*)(ws + 7 * SZ + 524288);
  bf16* W2c    = (bf16*)(ws + 7 * SZ + 1048576);
  bf16* smallc = (bf16*)(ws + 7 * SZ + 1572864);  // g1,b1,g2,b2,bf1,bf2 packed
  bf16* g1c  = smallc + 0;
  bf16* b1c  = smallc + 256;
  bf16* g2c  = smallc + 512;
  bf16* b2c  = smallc + 768;
  bf16* bf1c = smallc + 1024;
  bf16* bf2c = smallc + 2048;
  int*  flagp = (int*)(ws + 7 * SZ + 1581568);
  bf16* outsc = (bf16*)d_out;

  detect_kernel<<<1, 256, 0, stream>>>(d_in[0], flagp);
  cvt_all_kernel<<<3073, 256, 0, stream>>>(d_in[0], d_in[1], d_in[2], d_in[7], d_in[9],
                                           d_in[3], d_in[4], d_in[5], d_in[6], d_in[8], d_in[10],
                                           xc, Wqkvc, Wprojc, W1c, W2c, smallc, flagp);

  qkv_kernel<<<dim3(36, 12), 256, 0, stream>>>(xc, Wqkvc, Qc, Kc, Vt);
  rope_kernel<<<9216, 256, 0, stream>>>(Qc, Kc, Wp);
  attn_kernel<<<dim3(16, 36), 256, 0, stream>>>(Qc, Kc, Vt, AO);
  gemmT<256, 0, 2><<<dim3(72, 4), 256, 0, stream>>>(AO, Wprojc, nullptr, xc, outsc, 256);
  ln_kernel<<<2304, 256, 0, stream>>>(outsc, g1c, b1c, F);
  gemmT<256, 1, 4><<<dim3(36, 16), 256, 0, stream>>>(F, W1c, bf1c, nullptr, G, 1024);
  gemmT<1024, 2, 2><<<dim3(72, 4), 256, 0, stream>>>(G, W2c, bf2c, F, Y, 256);
  ln_out_kernel<<<2304, 256, 0, stream>>>(Y, g2c, b2c, d_out, flagp);
}